// Round 1
// baseline (29.490 us; speedup 1.0000x reference)
//
#include <hip/hip_runtime.h>

typedef float float4v __attribute__((ext_vector_type(4)));

__global__ __launch_bounds__(256) void spline_eval_kernel(
    const float* __restrict__ xin,
    const float* __restrict__ points,
    const float* __restrict__ values,
    float* __restrict__ out,
    int n4, int total)
{
    // Expanded per-interval cubic coefficients in x-basis: {a3,a2,a1,a0}
    __shared__ float4 sc[9];
    __shared__ float sp[10];

    if (threadIdx.x == 0) {
        // ---- tiny not-a-knot spline solve (tridiagonal -> Thomas), n = 10 ----
        float p[10], v[10];
#pragma unroll
        for (int k = 0; k < 10; ++k) { p[k] = points[k]; v[k] = values[k]; }
        float dx[9], sl[9];
#pragma unroll
        for (int k = 0; k < 9; ++k) { dx[k] = p[k + 1] - p[k]; sl[k] = (v[k + 1] - v[k]) / dx[k]; }

        float dg[10], lo[10], up[10], bb[10];
        float d0 = p[2] - p[0];
        dg[0] = dx[1]; up[0] = d0; lo[0] = 0.0f;
        bb[0] = ((dx[0] + 2.0f * d0) * dx[1] * sl[0] + dx[0] * dx[0] * sl[1]) / d0;
#pragma unroll
        for (int i = 1; i <= 8; ++i) {
            lo[i] = dx[i];
            dg[i] = 2.0f * (dx[i - 1] + dx[i]);
            up[i] = dx[i - 1];
            bb[i] = 3.0f * (dx[i] * sl[i - 1] + dx[i - 1] * sl[i]);
        }
        float dn = p[9] - p[7];
        lo[9] = dn; dg[9] = dx[7]; up[9] = 0.0f;
        bb[9] = (dx[8] * dx[8] * sl[7] + (2.0f * dn + dx[8]) * dx[7] * sl[8]) / dn;

        // Thomas forward elimination
        float cp[10], bp[10];
        cp[0] = up[0] / dg[0];
        bp[0] = bb[0] / dg[0];
#pragma unroll
        for (int i = 1; i <= 9; ++i) {
            float m = dg[i] - lo[i] * cp[i - 1];
            cp[i] = up[i] / m;
            bp[i] = (bb[i] - lo[i] * bp[i - 1]) / m;
        }
        float s[10];
        s[9] = bp[9];
#pragma unroll
        for (int i = 8; i >= 0; --i) s[i] = bp[i] - cp[i] * s[i + 1];

        // per-interval t-basis coeffs -> expand to global-x basis
#pragma unroll
        for (int i = 0; i < 9; ++i) {
            float tt = (s[i] + s[i + 1] - 2.0f * sl[i]) / dx[i];
            float c3 = tt / dx[i];
            float c2 = (sl[i] - s[i]) / dx[i] - tt;
            float c1 = s[i];
            float c0 = v[i];
            float pi = p[i];
            // y = c3 t^3 + c2 t^2 + c1 t + c0, t = x - pi  ==>
            float a3 = c3;
            float a2 = c2 - 3.0f * c3 * pi;
            float a1 = (3.0f * c3 * pi - 2.0f * c2) * pi + c1;
            float a0 = ((-c3 * pi + c2) * pi - c1) * pi + c0;
            sc[i] = make_float4(a3, a2, a1, a0);
        }
#pragma unroll
        for (int k = 0; k < 10; ++k) sp[k] = p[k];
    }
    __syncthreads();

    // knot thresholds for branchless searchsorted (i = sum of (x >= p_j), j=1..8)
    const float q1 = sp[1], q2 = sp[2], q3 = sp[3], q4 = sp[4];
    const float q5 = sp[5], q6 = sp[6], q7 = sp[7], q8 = sp[8];

    const float4v* __restrict__ x4 = (const float4v*)xin;
    float4v* __restrict__ o4 = (float4v*)out;

    int idx = blockIdx.x * blockDim.x + threadIdx.x;
    int stride = gridDim.x * blockDim.x;

    for (int vi = idx; vi < n4; vi += stride) {
        float4v xv = x4[vi];
        float4v yv;
#pragma unroll
        for (int j = 0; j < 4; ++j) {
            float xx = xv[j];
            int i = (xx >= q1) + (xx >= q2) + (xx >= q3) + (xx >= q4) +
                    (xx >= q5) + (xx >= q6) + (xx >= q7) + (xx >= q8);
            float4 c = sc[i];
            yv[j] = ((c.x * xx + c.y) * xx + c.z) * xx + c.w;
        }
        o4[vi] = yv;
    }

    // scalar tail (total not divisible by 4) — handled by block 0
    int tail = n4 * 4;
    if (blockIdx.x == 0) {
        for (int e = tail + threadIdx.x; e < total; e += blockDim.x) {
            float xx = xin[e];
            int i = (xx >= q1) + (xx >= q2) + (xx >= q3) + (xx >= q4) +
                    (xx >= q5) + (xx >= q6) + (xx >= q7) + (xx >= q8);
            float4 c = sc[i];
            out[e] = ((c.x * xx + c.y) * xx + c.z) * xx + c.w;
        }
    }
}

extern "C" void kernel_launch(void* const* d_in, const int* in_sizes, int n_in,
                              void* d_out, int out_size, void* d_ws, size_t ws_size,
                              hipStream_t stream) {
    const float* x = (const float*)d_in[0];
    const float* points = (const float*)d_in[1];
    const float* values = (const float*)d_in[2];
    float* out = (float*)d_out;

    int total = out_size;          // 4096*4096 = 16777216
    int n4 = total / 4;            // float4 elements

    const int block = 256;
    const int grid = 2048;         // 8 blocks/CU co-resident, grid-stride x8

    spline_eval_kernel<<<grid, block, 0, stream>>>(x, points, values, out, n4, total);
}